// Round 2
// baseline (826.163 us; speedup 1.0000x reference)
//
#include <hip/hip_runtime.h>

#define N_NODES 100000
#define N_EDGES 1600000
#define HD 128
#define SLOPE 0.2f

// ---------------------------------------------------------------------------
// K1: xp1 = emb[h] @ W1, fused e_src1/e_dst1 wave-reduce.
// One wave per row. Lane l holds output cols 2l and 2l+1.
// ---------------------------------------------------------------------------
__global__ __launch_bounds__(256) void gemm1_kernel(
    const int* __restrict__ h,
    const float* __restrict__ emb,
    const float* __restrict__ W1,
    const float* __restrict__ a_src1,
    const float* __restrict__ a_dst1,
    float* __restrict__ xp1,
    float* __restrict__ es1,
    float* __restrict__ ed1)
{
    const int wid = threadIdx.x >> 6;
    const int lane = threadIdx.x & 63;
    const int row = blockIdx.x * 4 + wid;
    if (row >= N_NODES) return;

    const int hrow = h[row];
    // x row: lane holds elements 2l (x) and 2l+1 (y)
    const float2* xrow = (const float2*)(emb + (size_t)hrow * HD);
    const float2 xp = xrow[lane];
    const float xlo = xp.x, xhi = xp.y;

    const float2* W1v = (const float2*)W1;
    float acc0 = 0.f, acc1 = 0.f;
    #pragma unroll 8
    for (int k = 0; k < HD; ++k) {
        const float xk = (k & 1) ? __shfl(xhi, k >> 1, 64) : __shfl(xlo, k >> 1, 64);
        const float2 w = W1v[k * (HD / 2) + lane];
        acc0 += xk * w.x;
        acc1 += xk * w.y;
    }

    const int c0 = lane * 2, c1 = lane * 2 + 1;
    float2* xrow_out = (float2*)(xp1 + (size_t)row * HD);
    xrow_out[lane] = make_float2(acc0, acc1);

    float ps = acc0 * a_src1[c0] + acc1 * a_src1[c1];
    float pd = acc0 * a_dst1[c0] + acc1 * a_dst1[c1];
    #pragma unroll
    for (int off = 32; off > 0; off >>= 1) {
        ps += __shfl_down(ps, off, 64);
        pd += __shfl_down(pd, off, 64);
    }
    if (lane == 0) { es1[row] = ps; ed1[row] = pd; }
}

// ---------------------------------------------------------------------------
// K2: zero acc1; denom1 = sw1 = exp(leaky(e_src+e_dst)) (self-loop term).
// Softmax max-shift is algebraically a no-op (logits are O(1)), so skipped.
// ---------------------------------------------------------------------------
__global__ __launch_bounds__(256) void init1_kernel(
    const float* __restrict__ es1, const float* __restrict__ ed1,
    float4* __restrict__ acc1v, float* __restrict__ denom1, float* __restrict__ sw1)
{
    const int idx = blockIdx.x * blockDim.x + threadIdx.x;
    if (idx < N_NODES * (HD / 4)) acc1v[idx] = make_float4(0.f, 0.f, 0.f, 0.f);
    if (idx < N_NODES) {
        const float s = es1[idx] + ed1[idx];
        const float l = s > 0.f ? s : SLOPE * s;
        const float w = __expf(l);
        denom1[idx] = w;
        sw1[idx] = w;
    }
}

// ---------------------------------------------------------------------------
// K3: edge scatter, layer 1. One wave per edge; masked edges (~89%) exit early.
// ---------------------------------------------------------------------------
__global__ __launch_bounds__(256) void edge1_kernel(
    const int* __restrict__ ei, const int* __restrict__ nt,
    const float* __restrict__ es1, const float* __restrict__ ed1,
    const float* __restrict__ xp1,
    float* __restrict__ denom1, float* __restrict__ acc1)
{
    const int wid = threadIdx.x >> 6;
    const int lane = threadIdx.x & 63;
    const int e = blockIdx.x * 4 + wid;
    if (e >= N_EDGES) return;

    const int src = ei[e];
    const int dst = ei[N_EDGES + e];
    if ((nt[src] | nt[dst]) != 0) return;   // types in {0,1,2}: both-zero mask

    const float logit = es1[src] + ed1[dst];
    const float l = logit > 0.f ? logit : SLOPE * logit;
    const float w = __expf(l);
    if (lane == 0) atomicAdd(denom1 + dst, w);

    const float* xs = xp1 + (size_t)src * HD;
    float* ad = acc1 + (size_t)dst * HD;
    atomicAdd(ad + lane,      w * xs[lane]);
    atomicAdd(ad + 64 + lane, w * xs[64 + lane]);
}

// ---------------------------------------------------------------------------
// K4: layer-1 epilogue (normalize + b1 + ReLU) fused with layer-2 GEMV
// (xp2 = x2 @ W2) and layer-2 self-loop init. One wave per node.
// x2 is never materialized.
// ---------------------------------------------------------------------------
__global__ __launch_bounds__(256) void node2_kernel(
    const float* __restrict__ xp1, const float* __restrict__ acc1,
    const float* __restrict__ denom1, const float* __restrict__ sw1,
    const float* __restrict__ b1, const float* __restrict__ W2,
    const float* __restrict__ a_src2, const float* __restrict__ a_dst2,
    float* __restrict__ xp2, float* __restrict__ denom2,
    float* __restrict__ sw2, float* __restrict__ acc2)
{
    const int wid = threadIdx.x >> 6;
    const int lane = threadIdx.x & 63;
    const int i = blockIdx.x * 4 + wid;
    if (i >= N_NODES) return;

    const float sw = sw1[i];
    const float inv = 1.f / denom1[i];
    const size_t base = (size_t)i * HD;

    const float a0 = acc1[base + lane],      a1 = acc1[base + 64 + lane];
    const float p0 = xp1[base + lane],       p1 = xp1[base + 64 + lane];
    float o0 = (a0 + sw * p0) * inv + b1[lane];
    float o1 = (a1 + sw * p1) * inv + b1[64 + lane];
    o0 = fmaxf(o0, 0.f);
    o1 = fmaxf(o1, 0.f);

    float part = o0 * W2[lane] + o1 * W2[64 + lane];
    #pragma unroll
    for (int off = 32; off > 0; off >>= 1) part += __shfl_down(part, off, 64);

    if (lane == 0) {
        xp2[i] = part;
        const float s = part * (a_src2[0] + a_dst2[0]);
        const float l = s > 0.f ? s : SLOPE * s;
        const float w = __expf(l);
        denom2[i] = w;
        sw2[i] = w;
        acc2[i] = 0.f;
    }
}

// ---------------------------------------------------------------------------
// K5: edge scatter, layer 2 (scalar features). One thread per edge.
// ---------------------------------------------------------------------------
__global__ __launch_bounds__(256) void edge2_kernel(
    const int* __restrict__ ei, const int* __restrict__ nt,
    const float* __restrict__ xp2,
    const float* __restrict__ a_src2, const float* __restrict__ a_dst2,
    float* __restrict__ denom2, float* __restrict__ acc2)
{
    const int e = blockIdx.x * blockDim.x + threadIdx.x;
    if (e >= N_EDGES) return;
    const int src = ei[e];
    const int dst = ei[N_EDGES + e];
    if ((nt[src] | nt[dst]) != 0) return;

    const float xs = xp2[src];
    const float logit = xs * a_src2[0] + xp2[dst] * a_dst2[0];
    const float l = logit > 0.f ? logit : SLOPE * logit;
    const float w = __expf(l);
    atomicAdd(denom2 + dst, w);
    atomicAdd(acc2 + dst, w * xs);
}

// ---------------------------------------------------------------------------
// K6: final normalize + b2, store f32.
// ---------------------------------------------------------------------------
__global__ __launch_bounds__(256) void final_kernel(
    const float* __restrict__ xp2, const float* __restrict__ acc2,
    const float* __restrict__ denom2, const float* __restrict__ sw2,
    const float* __restrict__ b2, float* __restrict__ out)
{
    const int i = blockIdx.x * blockDim.x + threadIdx.x;
    if (i >= N_NODES) return;
    out[i] = (acc2[i] + sw2[i] * xp2[i]) / denom2[i] + b2[0];
}

extern "C" void kernel_launch(void* const* d_in, const int* in_sizes, int n_in,
                              void* d_out, int out_size, void* d_ws, size_t ws_size,
                              hipStream_t stream)
{
    const int* h   = (const int*)d_in[0];
    const int* ei  = (const int*)d_in[1];
    const int* nt  = (const int*)d_in[2];
    const float* emb    = (const float*)d_in[3];
    const float* W1     = (const float*)d_in[4];
    const float* a_src1 = (const float*)d_in[5];
    const float* a_dst1 = (const float*)d_in[6];
    const float* b1     = (const float*)d_in[7];
    const float* W2     = (const float*)d_in[8];
    const float* a_src2 = (const float*)d_in[9];
    const float* a_dst2 = (const float*)d_in[10];
    const float* b2     = (const float*)d_in[11];
    float* out = (float*)d_out;

    char* ws = (char*)d_ws;
    size_t off = 0;
    float* xp1    = (float*)(ws + off); off += (size_t)N_NODES * HD * sizeof(float);
    float* acc1   = (float*)(ws + off); off += (size_t)N_NODES * HD * sizeof(float);
    float* es1    = (float*)(ws + off); off += (size_t)N_NODES * sizeof(float);
    float* ed1    = (float*)(ws + off); off += (size_t)N_NODES * sizeof(float);
    float* denom1 = (float*)(ws + off); off += (size_t)N_NODES * sizeof(float);
    float* sw1    = (float*)(ws + off); off += (size_t)N_NODES * sizeof(float);
    float* xp2    = (float*)(ws + off); off += (size_t)N_NODES * sizeof(float);
    float* denom2 = (float*)(ws + off); off += (size_t)N_NODES * sizeof(float);
    float* sw2    = (float*)(ws + off); off += (size_t)N_NODES * sizeof(float);
    float* acc2   = (float*)(ws + off); off += (size_t)N_NODES * sizeof(float);

    gemm1_kernel<<<(N_NODES + 3) / 4, 256, 0, stream>>>(
        h, emb, W1, a_src1, a_dst1, xp1, es1, ed1);
    init1_kernel<<<(N_NODES * (HD / 4) + 255) / 256, 256, 0, stream>>>(
        es1, ed1, (float4*)acc1, denom1, sw1);
    edge1_kernel<<<(N_EDGES + 3) / 4, 256, 0, stream>>>(
        ei, nt, es1, ed1, xp1, denom1, acc1);
    node2_kernel<<<(N_NODES + 3) / 4, 256, 0, stream>>>(
        xp1, acc1, denom1, sw1, b1, W2, a_src2, a_dst2, xp2, denom2, sw2, acc2);
    edge2_kernel<<<(N_EDGES + 255) / 256, 256, 0, stream>>>(
        ei, nt, xp2, a_src2, a_dst2, denom2, acc2);
    final_kernel<<<(N_NODES + 255) / 256, 256, 0, stream>>>(
        xp2, acc2, denom2, sw2, b2, out);
}

// Round 3
// 513.288 us; speedup vs baseline: 1.6096x; 1.6096x over previous
//
#include <hip/hip_runtime.h>

#define N_NODES 100000
#define N_EDGES 1600000
#define HD 128
#define SLOPE 0.2f
#define TM 32   // rows per block in gemm1 (100000 % 32 == 0... actually 100000/32=3125 exact)

// ---------------------------------------------------------------------------
// K1: xp1 = emb[h] @ W1 — LDS-tiled, 4x4 register micro-tiles.
// Fused epilogue: es1/ed1 (butterfly reduce over half-wave),
// denom1 = w_self = exp(leaky(es+ed)), and acc1 seeded with w_self * xp1
// (self-loop contribution), so no separate init kernel is needed and
// node2 never re-reads xp1.
// Layout: 256 thr = 8 row-groups (rgq=tid>>5, 4 rows each) x 32 col-groups
// (cg=tid&31, 4 cols each). A wave holds 2 rgq x 32 cg.
// ---------------------------------------------------------------------------
__global__ __launch_bounds__(256) void gemm1_kernel(
    const int* __restrict__ h,
    const float* __restrict__ emb,
    const float* __restrict__ W1,
    const float* __restrict__ a_src1,
    const float* __restrict__ a_dst1,
    float* __restrict__ xp1,
    float* __restrict__ acc1,
    float* __restrict__ es1,
    float* __restrict__ ed1,
    float* __restrict__ denom1)
{
    __shared__ float Wc[32 * HD];     // 16 KB: one 32-row K-chunk of W1
    __shared__ float XT[HD * 36];     // 18 KB: X tile transposed, pad 36
                                      //   (36*4=144 B rows: 16B-aligned, banks spread)

    const int tid  = threadIdx.x;
    const int row0 = blockIdx.x * TM;

    // ---- stage X tile: gather 32 rows of emb[h[.]], store transposed ----
    {
        const int r  = tid >> 3;            // 0..31 local row
        const int kb = (tid & 7) * 16;      // 16 consecutive floats
        const float4* src = (const float4*)(emb + (size_t)h[row0 + r] * HD + kb);
        #pragma unroll
        for (int j = 0; j < 4; ++j) {
            const float4 v = src[j];
            XT[(kb + 4 * j + 0) * 36 + r] = v.x;
            XT[(kb + 4 * j + 1) * 36 + r] = v.y;
            XT[(kb + 4 * j + 2) * 36 + r] = v.z;
            XT[(kb + 4 * j + 3) * 36 + r] = v.w;
        }
    }

    const int cg  = tid & 31;
    const int rgq = tid >> 5;
    const int c0  = cg * 4;
    const int r0  = rgq * 4;

    float acc[4][4] = {{0.f}};

    for (int kc = 0; kc < HD; kc += 32) {
        __syncthreads();                       // also covers initial X staging
        // stage W1 rows kc..kc+31 (4096 floats) — coalesced, linear LDS write
        const float4* wsrc = (const float4*)(W1 + kc * HD);
        float4* wdst = (float4*)Wc;
        #pragma unroll
        for (int j = 0; j < 4; ++j) wdst[tid + 256 * j] = wsrc[tid + 256 * j];
        __syncthreads();

        #pragma unroll
        for (int kk = 0; kk < 32; ++kk) {
            const float4 w = *(const float4*)(Wc + kk * HD + c0);
            const float4 x = *(const float4*)(XT + (kc + kk) * 36 + r0);
            acc[0][0] += x.x * w.x; acc[0][1] += x.x * w.y;
            acc[0][2] += x.x * w.z; acc[0][3] += x.x * w.w;
            acc[1][0] += x.y * w.x; acc[1][1] += x.y * w.y;
            acc[1][2] += x.y * w.z; acc[1][3] += x.y * w.w;
            acc[2][0] += x.z * w.x; acc[2][1] += x.z * w.y;
            acc[2][2] += x.z * w.z; acc[2][3] += x.z * w.w;
            acc[3][0] += x.w * w.x; acc[3][1] += x.w * w.y;
            acc[3][2] += x.w * w.z; acc[3][3] += x.w * w.w;
        }
    }

    // ---- fused epilogue ----
    const float4 as4 = *(const float4*)(a_src1 + c0);
    const float4 ad4 = *(const float4*)(a_dst1 + c0);
    float ps[4], pd[4];
    #pragma unroll
    for (int r = 0; r < 4; ++r) {
        ps[r] = acc[r][0] * as4.x + acc[r][1] * as4.y + acc[r][2] * as4.z + acc[r][3] * as4.w;
        pd[r] = acc[r][0] * ad4.x + acc[r][1] * ad4.y + acc[r][2] * ad4.z + acc[r][3] * ad4.w;
    }
    // butterfly over the 32 cg lanes (stays within each half-wave)
    #pragma unroll
    for (int m = 1; m < 32; m <<= 1) {
        #pragma unroll
        for (int r = 0; r < 4; ++r) {
            ps[r] += __shfl_xor(ps[r], m, 64);
            pd[r] += __shfl_xor(pd[r], m, 64);
        }
    }

    #pragma unroll
    for (int r = 0; r < 4; ++r) {
        const int row = row0 + r0 + r;
        const float s = ps[r] + pd[r];
        const float l = s > 0.f ? s : SLOPE * s;
        const float w = __expf(l);
        const float4 v = make_float4(acc[r][0], acc[r][1], acc[r][2], acc[r][3]);
        *(float4*)(xp1  + (size_t)row * HD + c0) = v;
        *(float4*)(acc1 + (size_t)row * HD + c0) =
            make_float4(w * v.x, w * v.y, w * v.z, w * v.w);
        if (cg == 0) {
            es1[row] = ps[r];
            ed1[row] = pd[r];
            denom1[row] = w;      // self-loop weight
        }
    }
}

// ---------------------------------------------------------------------------
// K3: edge scatter, layer 1. One wave per edge; masked edges (~89%) exit early.
// ---------------------------------------------------------------------------
__global__ __launch_bounds__(256) void edge1_kernel(
    const int* __restrict__ ei, const int* __restrict__ nt,
    const float* __restrict__ es1, const float* __restrict__ ed1,
    const float* __restrict__ xp1,
    float* __restrict__ denom1, float* __restrict__ acc1)
{
    const int wid = threadIdx.x >> 6;
    const int lane = threadIdx.x & 63;
    const int e = blockIdx.x * 4 + wid;
    if (e >= N_EDGES) return;

    const int src = ei[e];
    const int dst = ei[N_EDGES + e];
    if ((nt[src] | nt[dst]) != 0) return;   // types in {0,1,2}: both-zero mask

    const float logit = es1[src] + ed1[dst];
    const float l = logit > 0.f ? logit : SLOPE * logit;
    const float w = __expf(l);
    if (lane == 0) atomicAdd(denom1 + dst, w);

    const float* xs = xp1 + (size_t)src * HD;
    float* ad = acc1 + (size_t)dst * HD;
    atomicAdd(ad + lane,      w * xs[lane]);
    atomicAdd(ad + 64 + lane, w * xs[64 + lane]);
}

// ---------------------------------------------------------------------------
// K4: layer-1 normalize (+b1, ReLU) fused with layer-2 GEMV and layer-2
// self-loop init. One wave per node. acc1 already contains the self term.
// ---------------------------------------------------------------------------
__global__ __launch_bounds__(256) void node2_kernel(
    const float* __restrict__ acc1, const float* __restrict__ denom1,
    const float* __restrict__ b1, const float* __restrict__ W2,
    const float* __restrict__ a_src2, const float* __restrict__ a_dst2,
    float* __restrict__ xp2, float* __restrict__ denom2,
    float* __restrict__ sw2, float* __restrict__ acc2)
{
    const int wid = threadIdx.x >> 6;
    const int lane = threadIdx.x & 63;
    const int i = blockIdx.x * 4 + wid;
    if (i >= N_NODES) return;

    const float inv = 1.f / denom1[i];
    const size_t base = (size_t)i * HD;

    float o0 = acc1[base + lane]      * inv + b1[lane];
    float o1 = acc1[base + 64 + lane] * inv + b1[64 + lane];
    o0 = fmaxf(o0, 0.f);
    o1 = fmaxf(o1, 0.f);

    float part = o0 * W2[lane] + o1 * W2[64 + lane];
    #pragma unroll
    for (int off = 32; off > 0; off >>= 1) part += __shfl_down(part, off, 64);

    if (lane == 0) {
        xp2[i] = part;
        const float s = part * (a_src2[0] + a_dst2[0]);
        const float l = s > 0.f ? s : SLOPE * s;
        const float w = __expf(l);
        denom2[i] = w;
        sw2[i] = w;
        acc2[i] = 0.f;
    }
}

// ---------------------------------------------------------------------------
// K5: edge scatter, layer 2 (scalar features). One thread per edge.
// ---------------------------------------------------------------------------
__global__ __launch_bounds__(256) void edge2_kernel(
    const int* __restrict__ ei, const int* __restrict__ nt,
    const float* __restrict__ xp2,
    const float* __restrict__ a_src2, const float* __restrict__ a_dst2,
    float* __restrict__ denom2, float* __restrict__ acc2)
{
    const int e = blockIdx.x * blockDim.x + threadIdx.x;
    if (e >= N_EDGES) return;
    const int src = ei[e];
    const int dst = ei[N_EDGES + e];
    if ((nt[src] | nt[dst]) != 0) return;

    const float xs = xp2[src];
    const float logit = xs * a_src2[0] + xp2[dst] * a_dst2[0];
    const float l = logit > 0.f ? logit : SLOPE * logit;
    const float w = __expf(l);
    atomicAdd(denom2 + dst, w);
    atomicAdd(acc2 + dst, w * xs);
}

// ---------------------------------------------------------------------------
// K6: final normalize + b2, store f32.
// ---------------------------------------------------------------------------
__global__ __launch_bounds__(256) void final_kernel(
    const float* __restrict__ xp2, const float* __restrict__ acc2,
    const float* __restrict__ denom2, const float* __restrict__ sw2,
    const float* __restrict__ b2, float* __restrict__ out)
{
    const int i = blockIdx.x * blockDim.x + threadIdx.x;
    if (i >= N_NODES) return;
    out[i] = (acc2[i] + sw2[i] * xp2[i]) / denom2[i] + b2[0];
}

extern "C" void kernel_launch(void* const* d_in, const int* in_sizes, int n_in,
                              void* d_out, int out_size, void* d_ws, size_t ws_size,
                              hipStream_t stream)
{
    const int* h   = (const int*)d_in[0];
    const int* ei  = (const int*)d_in[1];
    const int* nt  = (const int*)d_in[2];
    const float* emb    = (const float*)d_in[3];
    const float* W1     = (const float*)d_in[4];
    const float* a_src1 = (const float*)d_in[5];
    const float* a_dst1 = (const float*)d_in[6];
    const float* b1     = (const float*)d_in[7];
    const float* W2     = (const float*)d_in[8];
    const float* a_src2 = (const float*)d_in[9];
    const float* a_dst2 = (const float*)d_in[10];
    const float* b2     = (const float*)d_in[11];
    float* out = (float*)d_out;

    char* ws = (char*)d_ws;
    size_t off = 0;
    float* xp1    = (float*)(ws + off); off += (size_t)N_NODES * HD * sizeof(float);
    float* acc1   = (float*)(ws + off); off += (size_t)N_NODES * HD * sizeof(float);
    float* es1    = (float*)(ws + off); off += (size_t)N_NODES * sizeof(float);
    float* ed1    = (float*)(ws + off); off += (size_t)N_NODES * sizeof(float);
    float* denom1 = (float*)(ws + off); off += (size_t)N_NODES * sizeof(float);
    float* xp2    = (float*)(ws + off); off += (size_t)N_NODES * sizeof(float);
    float* denom2 = (float*)(ws + off); off += (size_t)N_NODES * sizeof(float);
    float* sw2    = (float*)(ws + off); off += (size_t)N_NODES * sizeof(float);
    float* acc2   = (float*)(ws + off); off += (size_t)N_NODES * sizeof(float);

    // 100000 = 3125 * 32 exactly
    gemm1_kernel<<<N_NODES / TM, 256, 0, stream>>>(
        h, emb, W1, a_src1, a_dst1, xp1, acc1, es1, ed1, denom1);
    edge1_kernel<<<(N_EDGES + 3) / 4, 256, 0, stream>>>(
        ei, nt, es1, ed1, xp1, denom1, acc1);
    node2_kernel<<<(N_NODES + 3) / 4, 256, 0, stream>>>(
        acc1, denom1, b1, W2, a_src2, a_dst2, xp2, denom2, sw2, acc2);
    edge2_kernel<<<(N_EDGES + 255) / 256, 256, 0, stream>>>(
        ei, nt, xp2, a_src2, a_dst2, denom2, acc2);
    final_kernel<<<(N_NODES + 255) / 256, 256, 0, stream>>>(
        xp2, acc2, denom2, sw2, b2, out);
}

// Round 4
// 257.234 us; speedup vs baseline: 3.2117x; 1.9954x over previous
//
#include <hip/hip_runtime.h>

#define N_NODES 100000
#define N_EDGES 1600000
#define HD 128
#define SLOPE 0.2f
#define TM 32
#define NBLK 391   // ceil(N_NODES/256)

// ---------------------------------------------------------------------------
// K1: xp1 = emb[h] @ W1 — LDS-tiled, 4x4 register micro-tiles.
// Fused: es1/ed1 attention dots and denom1 = w_self = exp(leaky(es+ed)).
// ---------------------------------------------------------------------------
__global__ __launch_bounds__(256) void gemm1_kernel(
    const int* __restrict__ h,
    const float* __restrict__ emb,
    const float* __restrict__ W1,
    const float* __restrict__ a_src1,
    const float* __restrict__ a_dst1,
    float* __restrict__ xp1,
    float* __restrict__ es1,
    float* __restrict__ ed1,
    float* __restrict__ denom1)
{
    __shared__ float Wc[32 * HD];
    __shared__ float XT[HD * 36];

    const int tid  = threadIdx.x;
    const int row0 = blockIdx.x * TM;

    {
        const int r  = tid >> 3;
        const int kb = (tid & 7) * 16;
        const float4* src = (const float4*)(emb + (size_t)h[row0 + r] * HD + kb);
        #pragma unroll
        for (int j = 0; j < 4; ++j) {
            const float4 v = src[j];
            XT[(kb + 4 * j + 0) * 36 + r] = v.x;
            XT[(kb + 4 * j + 1) * 36 + r] = v.y;
            XT[(kb + 4 * j + 2) * 36 + r] = v.z;
            XT[(kb + 4 * j + 3) * 36 + r] = v.w;
        }
    }

    const int cg  = tid & 31;
    const int rgq = tid >> 5;
    const int c0  = cg * 4;
    const int r0  = rgq * 4;

    float acc[4][4] = {{0.f}};

    for (int kc = 0; kc < HD; kc += 32) {
        __syncthreads();
        const float4* wsrc = (const float4*)(W1 + kc * HD);
        float4* wdst = (float4*)Wc;
        #pragma unroll
        for (int j = 0; j < 4; ++j) wdst[tid + 256 * j] = wsrc[tid + 256 * j];
        __syncthreads();

        #pragma unroll
        for (int kk = 0; kk < 32; ++kk) {
            const float4 w = *(const float4*)(Wc + kk * HD + c0);
            const float4 x = *(const float4*)(XT + (kc + kk) * 36 + r0);
            acc[0][0] += x.x * w.x; acc[0][1] += x.x * w.y;
            acc[0][2] += x.x * w.z; acc[0][3] += x.x * w.w;
            acc[1][0] += x.y * w.x; acc[1][1] += x.y * w.y;
            acc[1][2] += x.y * w.z; acc[1][3] += x.y * w.w;
            acc[2][0] += x.z * w.x; acc[2][1] += x.z * w.y;
            acc[2][2] += x.z * w.z; acc[2][3] += x.z * w.w;
            acc[3][0] += x.w * w.x; acc[3][1] += x.w * w.y;
            acc[3][2] += x.w * w.z; acc[3][3] += x.w * w.w;
        }
    }

    const float4 as4 = *(const float4*)(a_src1 + c0);
    const float4 ad4 = *(const float4*)(a_dst1 + c0);
    float ps[4], pd[4];
    #pragma unroll
    for (int r = 0; r < 4; ++r) {
        ps[r] = acc[r][0] * as4.x + acc[r][1] * as4.y + acc[r][2] * as4.z + acc[r][3] * as4.w;
        pd[r] = acc[r][0] * ad4.x + acc[r][1] * ad4.y + acc[r][2] * ad4.z + acc[r][3] * ad4.w;
    }
    #pragma unroll
    for (int m = 1; m < 32; m <<= 1) {
        #pragma unroll
        for (int r = 0; r < 4; ++r) {
            ps[r] += __shfl_xor(ps[r], m, 64);
            pd[r] += __shfl_xor(pd[r], m, 64);
        }
    }

    #pragma unroll
    for (int r = 0; r < 4; ++r) {
        const int row = row0 + r0 + r;
        *(float4*)(xp1 + (size_t)row * HD + c0) =
            make_float4(acc[r][0], acc[r][1], acc[r][2], acc[r][3]);
        if (cg == 0) {
            const float s = ps[r] + pd[r];
            const float l = s > 0.f ? s : SLOPE * s;
            es1[row] = ps[r];
            ed1[row] = pd[r];
            denom1[row] = __expf(l);   // self-loop weight
        }
    }
}

// ---------------------------------------------------------------------------
// CSR build: zero -> histogram -> block sums -> block scan -> rowptr -> scatter
// ---------------------------------------------------------------------------
__global__ __launch_bounds__(256) void zero_kernel(int* __restrict__ deg, int* __restrict__ fill) {
    const int i = blockIdx.x * 256 + threadIdx.x;
    if (i < N_NODES) { deg[i] = 0; fill[i] = 0; }
}

__global__ __launch_bounds__(256) void hist_kernel(
    const int* __restrict__ ei, const int* __restrict__ nt, int* __restrict__ deg)
{
    const int e = blockIdx.x * 256 + threadIdx.x;
    if (e >= N_EDGES) return;
    const int src = ei[e];
    const int dst = ei[N_EDGES + e];
    if ((nt[src] | nt[dst]) != 0) return;
    atomicAdd(deg + dst, 1);
}

__global__ __launch_bounds__(256) void bsum_kernel(
    const int* __restrict__ deg, int* __restrict__ bsum)
{
    __shared__ int wsum[4];
    const int i = blockIdx.x * 256 + threadIdx.x;
    int v = (i < N_NODES) ? deg[i] : 0;
    #pragma unroll
    for (int off = 32; off > 0; off >>= 1) v += __shfl_down(v, off, 64);
    if ((threadIdx.x & 63) == 0) wsum[threadIdx.x >> 6] = v;
    __syncthreads();
    if (threadIdx.x == 0) bsum[blockIdx.x] = wsum[0] + wsum[1] + wsum[2] + wsum[3];
}

__global__ __launch_bounds__(512) void bscan_kernel(
    const int* __restrict__ bsum, int* __restrict__ bscan, int* __restrict__ rowptr)
{
    __shared__ int s[512];
    const int t = threadIdx.x;
    const int v = (t < NBLK) ? bsum[t] : 0;
    s[t] = v;
    __syncthreads();
    #pragma unroll
    for (int off = 1; off < 512; off <<= 1) {
        const int u = (t >= off) ? s[t - off] : 0;
        __syncthreads();
        s[t] += u;
        __syncthreads();
    }
    if (t < NBLK) bscan[t] = s[t] - v;            // exclusive
    if (t == 0) rowptr[N_NODES] = s[NBLK - 1];    // total active edges
}

__global__ __launch_bounds__(256) void rowptr_kernel(
    const int* __restrict__ deg, const int* __restrict__ bscan, int* __restrict__ rowptr)
{
    __shared__ int s[256];
    const int t = threadIdx.x;
    const int i = blockIdx.x * 256 + t;
    const int v = (i < N_NODES) ? deg[i] : 0;
    s[t] = v;
    __syncthreads();
    #pragma unroll
    for (int off = 1; off < 256; off <<= 1) {
        const int u = (t >= off) ? s[t - off] : 0;
        __syncthreads();
        s[t] += u;
        __syncthreads();
    }
    if (i < N_NODES) rowptr[i] = bscan[blockIdx.x] + s[t] - v;   // exclusive
}

__global__ __launch_bounds__(256) void scatter_kernel(
    const int* __restrict__ ei, const int* __restrict__ nt,
    const float* __restrict__ es1, const float* __restrict__ ed1,
    const int* __restrict__ rowptr, int* __restrict__ fill,
    int* __restrict__ esrc, float* __restrict__ ew)
{
    const int e = blockIdx.x * 256 + threadIdx.x;
    if (e >= N_EDGES) return;
    const int src = ei[e];
    const int dst = ei[N_EDGES + e];
    if ((nt[src] | nt[dst]) != 0) return;
    const float logit = es1[src] + ed1[dst];
    const float l = logit > 0.f ? logit : SLOPE * logit;
    const int slot = rowptr[dst] + atomicAdd(fill + dst, 1);
    esrc[slot] = src;
    ew[slot] = __expf(l);
}

// ---------------------------------------------------------------------------
// Gather layer 1 (one wave per node): register-accumulated weighted mean over
// in-edges + self loop, then normalize + b1 + ReLU + W2 GEMV -> xp2.
// No atomics. Lane l handles components 2l, 2l+1 (coalesced float2).
// ---------------------------------------------------------------------------
__global__ __launch_bounds__(256) void gather1_kernel(
    const float* __restrict__ xp1, const float* __restrict__ denom1,
    const int* __restrict__ rowptr, const int* __restrict__ esrc,
    const float* __restrict__ ew,
    const float* __restrict__ b1, const float* __restrict__ W2,
    float* __restrict__ xp2)
{
    const int wid = threadIdx.x >> 6;
    const int lane = threadIdx.x & 63;
    const int i = blockIdx.x * 4 + wid;
    if (i >= N_NODES) return;

    const int begin = rowptr[i];
    const int end   = rowptr[i + 1];
    const float wself = denom1[i];

    const float2 xs = ((const float2*)(xp1 + (size_t)i * HD))[lane];
    float a0 = wself * xs.x, a1 = wself * xs.y;
    float denom = wself;

    for (int j = begin; j < end; ++j) {
        const int s = esrc[j];
        const float w = ew[j];
        const float2 v = ((const float2*)(xp1 + (size_t)s * HD))[lane];
        a0 += w * v.x;
        a1 += w * v.y;
        denom += w;
    }

    const float inv = 1.f / denom;
    const float o0 = fmaxf(a0 * inv + b1[2 * lane],     0.f);
    const float o1 = fmaxf(a1 * inv + b1[2 * lane + 1], 0.f);

    float part = o0 * W2[2 * lane] + o1 * W2[2 * lane + 1];
    #pragma unroll
    for (int off = 32; off > 0; off >>= 1) part += __shfl_down(part, off, 64);
    if (lane == 0) xp2[i] = part;
}

// ---------------------------------------------------------------------------
// Layer 2 over scalars (one thread per node): reuse the same CSR.
// ---------------------------------------------------------------------------
__global__ __launch_bounds__(256) void final2_kernel(
    const float* __restrict__ xp2, const int* __restrict__ rowptr,
    const int* __restrict__ esrc,
    const float* __restrict__ a_src2, const float* __restrict__ a_dst2,
    const float* __restrict__ b2, float* __restrict__ out)
{
    const int i = blockIdx.x * 256 + threadIdx.x;
    if (i >= N_NODES) return;

    const float as = a_src2[0], ad = a_dst2[0];
    const float xi = xp2[i];
    const float s0 = (as + ad) * xi;
    const float l0 = s0 > 0.f ? s0 : SLOPE * s0;
    const float wself = __expf(l0);

    float denom = wself, num = wself * xi;
    const int end = rowptr[i + 1];
    for (int j = rowptr[i]; j < end; ++j) {
        const float xsv = xp2[esrc[j]];
        const float lg = as * xsv + ad * xi;
        const float ll = lg > 0.f ? lg : SLOPE * lg;
        const float w = __expf(ll);
        denom += w;
        num += w * xsv;
    }
    out[i] = num / denom + b2[0];
}

extern "C" void kernel_launch(void* const* d_in, const int* in_sizes, int n_in,
                              void* d_out, int out_size, void* d_ws, size_t ws_size,
                              hipStream_t stream)
{
    const int* h   = (const int*)d_in[0];
    const int* ei  = (const int*)d_in[1];
    const int* nt  = (const int*)d_in[2];
    const float* emb    = (const float*)d_in[3];
    const float* W1     = (const float*)d_in[4];
    const float* a_src1 = (const float*)d_in[5];
    const float* a_dst1 = (const float*)d_in[6];
    const float* b1     = (const float*)d_in[7];
    const float* W2     = (const float*)d_in[8];
    const float* a_src2 = (const float*)d_in[9];
    const float* a_dst2 = (const float*)d_in[10];
    const float* b2     = (const float*)d_in[11];
    float* out = (float*)d_out;

    char* ws = (char*)d_ws;
    size_t off = 0;
    float* xp1    = (float*)(ws + off); off += (size_t)N_NODES * HD * sizeof(float);
    float* es1    = (float*)(ws + off); off += (size_t)N_NODES * sizeof(float);
    float* ed1    = (float*)(ws + off); off += (size_t)N_NODES * sizeof(float);
    float* denom1 = (float*)(ws + off); off += (size_t)N_NODES * sizeof(float);
    float* xp2    = (float*)(ws + off); off += (size_t)N_NODES * sizeof(float);
    int*   deg    = (int*)(ws + off);   off += (size_t)N_NODES * sizeof(int);
    int*   fill   = (int*)(ws + off);   off += (size_t)N_NODES * sizeof(int);
    int*   rowptr = (int*)(ws + off);   off += ((size_t)N_NODES + 1) * sizeof(int);
    int*   bsum   = (int*)(ws + off);   off += (size_t)NBLK * sizeof(int);
    int*   bscan  = (int*)(ws + off);   off += (size_t)NBLK * sizeof(int);
    int*   esrc   = (int*)(ws + off);   off += (size_t)N_EDGES * sizeof(int);
    float* ew     = (float*)(ws + off); off += (size_t)N_EDGES * sizeof(float);

    gemm1_kernel<<<N_NODES / TM, 256, 0, stream>>>(
        h, emb, W1, a_src1, a_dst1, xp1, es1, ed1, denom1);
    zero_kernel<<<NBLK, 256, 0, stream>>>(deg, fill);
    hist_kernel<<<(N_EDGES + 255) / 256, 256, 0, stream>>>(ei, nt, deg);
    bsum_kernel<<<NBLK, 256, 0, stream>>>(deg, bsum);
    bscan_kernel<<<1, 512, 0, stream>>>(bsum, bscan, rowptr);
    rowptr_kernel<<<NBLK, 256, 0, stream>>>(deg, bscan, rowptr);
    scatter_kernel<<<(N_EDGES + 255) / 256, 256, 0, stream>>>(
        ei, nt, es1, ed1, rowptr, fill, esrc, ew);
    gather1_kernel<<<(N_NODES + 3) / 4, 256, 0, stream>>>(
        xp1, denom1, rowptr, esrc, ew, b1, W2, xp2);
    final2_kernel<<<NBLK, 256, 0, stream>>>(
        xp2, rowptr, esrc, a_src2, a_dst2, b2, out);
}

// Round 5
// 252.630 us; speedup vs baseline: 3.2703x; 1.0182x over previous
//
#include <hip/hip_runtime.h>

#define N_NODES 100000
#define N_EDGES 1600000
#define HD 128
#define SLOPE 0.2f
#define TM 32
#define XP 132   // Xs row pitch (floats): 128+4, keeps 16B alignment
#define NBLK 391 // ceil(N_NODES/256)

// ---------------------------------------------------------------------------
// K1: xp1 = emb[h] @ W1 — LDS-tiled, 4x4x4 inner-product micro-kernel.
// X tile staged ROW-MAJOR once (no transpose): compute reads X via b128
// broadcast (32 lanes same address) and Wc via stride-16B b128 — both
// conflict-free. Fused: es1/ed1 dots and denom1 = w_self.
// ---------------------------------------------------------------------------
__global__ __launch_bounds__(256) void gemm1_kernel(
    const int* __restrict__ h,
    const float* __restrict__ emb,
    const float* __restrict__ W1,
    const float* __restrict__ a_src1,
    const float* __restrict__ a_dst1,
    float* __restrict__ xp1,
    float* __restrict__ es1,
    float* __restrict__ ed1,
    float* __restrict__ denom1)
{
    __shared__ float Wc[32 * HD];     // 16 KB: one 32-row K-chunk of W1
    __shared__ float Xs[TM * XP];     // 16.9 KB: X tile, row-major, full K

    const int tid  = threadIdx.x;
    const int row0 = blockIdx.x * TM;

    // ---- stage X tile row-major: thread (r=tid>>3, m=tid&7) loads 4xfloat4
    // at cols m*4 + 32j  (8 lanes cover 128B contiguous per j — coalesced) ----
    {
        const int r = tid >> 3;
        const int m = tid & 7;
        const float* src = emb + (size_t)h[row0 + r] * HD;
        float* dstrow = Xs + r * XP;
        #pragma unroll
        for (int j = 0; j < 4; ++j) {
            const int c = m * 4 + 32 * j;
            *(float4*)(dstrow + c) = *(const float4*)(src + c);
        }
    }

    const int cg  = tid & 31;
    const int rgq = tid >> 5;
    const int c0  = cg * 4;
    const int r0  = rgq * 4;

    float acc[4][4] = {{0.f}};

    for (int kc = 0; kc < HD; kc += 32) {
        __syncthreads();                       // also covers initial X staging
        const float4* wsrc = (const float4*)(W1 + kc * HD);
        float4* wdst = (float4*)Wc;
        #pragma unroll
        for (int j = 0; j < 4; ++j) wdst[tid + 256 * j] = wsrc[tid + 256 * j];
        __syncthreads();

        #pragma unroll
        for (int kk = 0; kk < 32; kk += 4) {
            float4 xv[4], wv[4];
            #pragma unroll
            for (int r = 0; r < 4; ++r)
                xv[r] = *(const float4*)(Xs + (r0 + r) * XP + kc + kk);
            #pragma unroll
            for (int t = 0; t < 4; ++t)
                wv[t] = *(const float4*)(Wc + (kk + t) * HD + c0);
            #pragma unroll
            for (int r = 0; r < 4; ++r) {
                acc[r][0] += xv[r].x * wv[0].x; acc[r][1] += xv[r].x * wv[0].y;
                acc[r][2] += xv[r].x * wv[0].z; acc[r][3] += xv[r].x * wv[0].w;
                acc[r][0] += xv[r].y * wv[1].x; acc[r][1] += xv[r].y * wv[1].y;
                acc[r][2] += xv[r].y * wv[1].z; acc[r][3] += xv[r].y * wv[1].w;
                acc[r][0] += xv[r].z * wv[2].x; acc[r][1] += xv[r].z * wv[2].y;
                acc[r][2] += xv[r].z * wv[2].z; acc[r][3] += xv[r].z * wv[2].w;
                acc[r][0] += xv[r].w * wv[3].x; acc[r][1] += xv[r].w * wv[3].y;
                acc[r][2] += xv[r].w * wv[3].z; acc[r][3] += xv[r].w * wv[3].w;
            }
        }
    }

    const float4 as4 = *(const float4*)(a_src1 + c0);
    const float4 ad4 = *(const float4*)(a_dst1 + c0);
    float ps[4], pd[4];
    #pragma unroll
    for (int r = 0; r < 4; ++r) {
        ps[r] = acc[r][0] * as4.x + acc[r][1] * as4.y + acc[r][2] * as4.z + acc[r][3] * as4.w;
        pd[r] = acc[r][0] * ad4.x + acc[r][1] * ad4.y + acc[r][2] * ad4.z + acc[r][3] * ad4.w;
    }
    #pragma unroll
    for (int m = 1; m < 32; m <<= 1) {
        #pragma unroll
        for (int r = 0; r < 4; ++r) {
            ps[r] += __shfl_xor(ps[r], m, 64);
            pd[r] += __shfl_xor(pd[r], m, 64);
        }
    }

    #pragma unroll
    for (int r = 0; r < 4; ++r) {
        const int row = row0 + r0 + r;
        *(float4*)(xp1 + (size_t)row * HD + c0) =
            make_float4(acc[r][0], acc[r][1], acc[r][2], acc[r][3]);
        if (cg == 0) {
            const float s = ps[r] + pd[r];
            const float l = s > 0.f ? s : SLOPE * s;
            es1[row] = ps[r];
            ed1[row] = pd[r];
            denom1[row] = __expf(l);   // self-loop weight
        }
    }
}

// ---------------------------------------------------------------------------
// CSR build: zero -> histogram -> block sums -> block scan -> rowptr -> scatter
// ---------------------------------------------------------------------------
__global__ __launch_bounds__(256) void zero_kernel(int* __restrict__ deg, int* __restrict__ fill) {
    const int i = blockIdx.x * 256 + threadIdx.x;
    if (i < N_NODES) { deg[i] = 0; fill[i] = 0; }
}

__global__ __launch_bounds__(256) void hist_kernel(
    const int* __restrict__ ei, const int* __restrict__ nt, int* __restrict__ deg)
{
    const int e = blockIdx.x * 256 + threadIdx.x;
    if (e >= N_EDGES) return;
    const int src = ei[e];
    const int dst = ei[N_EDGES + e];
    if ((nt[src] | nt[dst]) != 0) return;
    atomicAdd(deg + dst, 1);
}

__global__ __launch_bounds__(256) void bsum_kernel(
    const int* __restrict__ deg, int* __restrict__ bsum)
{
    __shared__ int wsum[4];
    const int i = blockIdx.x * 256 + threadIdx.x;
    int v = (i < N_NODES) ? deg[i] : 0;
    #pragma unroll
    for (int off = 32; off > 0; off >>= 1) v += __shfl_down(v, off, 64);
    if ((threadIdx.x & 63) == 0) wsum[threadIdx.x >> 6] = v;
    __syncthreads();
    if (threadIdx.x == 0) bsum[blockIdx.x] = wsum[0] + wsum[1] + wsum[2] + wsum[3];
}

__global__ __launch_bounds__(512) void bscan_kernel(
    const int* __restrict__ bsum, int* __restrict__ bscan, int* __restrict__ rowptr)
{
    __shared__ int s[512];
    const int t = threadIdx.x;
    const int v = (t < NBLK) ? bsum[t] : 0;
    s[t] = v;
    __syncthreads();
    #pragma unroll
    for (int off = 1; off < 512; off <<= 1) {
        const int u = (t >= off) ? s[t - off] : 0;
        __syncthreads();
        s[t] += u;
        __syncthreads();
    }
    if (t < NBLK) bscan[t] = s[t] - v;            // exclusive
    if (t == 0) rowptr[N_NODES] = s[NBLK - 1];    // total active edges
}

__global__ __launch_bounds__(256) void rowptr_kernel(
    const int* __restrict__ deg, const int* __restrict__ bscan, int* __restrict__ rowptr)
{
    __shared__ int s[256];
    const int t = threadIdx.x;
    const int i = blockIdx.x * 256 + t;
    const int v = (i < N_NODES) ? deg[i] : 0;
    s[t] = v;
    __syncthreads();
    #pragma unroll
    for (int off = 1; off < 256; off <<= 1) {
        const int u = (t >= off) ? s[t - off] : 0;
        __syncthreads();
        s[t] += u;
        __syncthreads();
    }
    if (i < N_NODES) rowptr[i] = bscan[blockIdx.x] + s[t] - v;   // exclusive
}

__global__ __launch_bounds__(256) void scatter_kernel(
    const int* __restrict__ ei, const int* __restrict__ nt,
    const float* __restrict__ es1, const float* __restrict__ ed1,
    const int* __restrict__ rowptr, int* __restrict__ fill,
    int* __restrict__ esrc, float* __restrict__ ew)
{
    const int e = blockIdx.x * 256 + threadIdx.x;
    if (e >= N_EDGES) return;
    const int src = ei[e];
    const int dst = ei[N_EDGES + e];
    if ((nt[src] | nt[dst]) != 0) return;
    const float logit = es1[src] + ed1[dst];
    const float l = logit > 0.f ? logit : SLOPE * logit;
    const int slot = rowptr[dst] + atomicAdd(fill + dst, 1);
    esrc[slot] = src;
    ew[slot] = __expf(l);
}

// ---------------------------------------------------------------------------
// Gather layer 1 (one wave per node): register-accumulated weighted mean over
// in-edges + self loop, normalize + b1 + ReLU + W2 GEMV -> xp2. No atomics.
// Software-pipelined: next (esrc, ew) loads issue before current row use.
// ---------------------------------------------------------------------------
__global__ __launch_bounds__(256) void gather1_kernel(
    const float* __restrict__ xp1, const float* __restrict__ denom1,
    const int* __restrict__ rowptr, const int* __restrict__ esrc,
    const float* __restrict__ ew,
    const float* __restrict__ b1, const float* __restrict__ W2,
    float* __restrict__ xp2)
{
    const int wid = threadIdx.x >> 6;
    const int lane = threadIdx.x & 63;
    const int i = blockIdx.x * 4 + wid;
    if (i >= N_NODES) return;

    const int begin = rowptr[i];
    const int end   = rowptr[i + 1];
    const float wself = denom1[i];

    const float2 xs = ((const float2*)(xp1 + (size_t)i * HD))[lane];
    float a0 = wself * xs.x, a1 = wself * xs.y;
    float denom = wself;

    int sN = 0; float wN = 0.f;
    if (begin < end) { sN = esrc[begin]; wN = ew[begin]; }
    for (int j = begin; j < end; ++j) {
        const int s = sN; const float w = wN;
        if (j + 1 < end) { sN = esrc[j + 1]; wN = ew[j + 1]; }
        const float2 v = ((const float2*)(xp1 + (size_t)s * HD))[lane];
        a0 += w * v.x;
        a1 += w * v.y;
        denom += w;
    }

    const float inv = 1.f / denom;
    const float o0 = fmaxf(a0 * inv + b1[2 * lane],     0.f);
    const float o1 = fmaxf(a1 * inv + b1[2 * lane + 1], 0.f);

    float part = o0 * W2[2 * lane] + o1 * W2[2 * lane + 1];
    #pragma unroll
    for (int off = 32; off > 0; off >>= 1) part += __shfl_down(part, off, 64);
    if (lane == 0) xp2[i] = part;
}

// ---------------------------------------------------------------------------
// Layer 2 over scalars (one thread per node): reuse the same CSR.
// ---------------------------------------------------------------------------
__global__ __launch_bounds__(256) void final2_kernel(
    const float* __restrict__ xp2, const int* __restrict__ rowptr,
    const int* __restrict__ esrc,
    const float* __restrict__ a_src2, const float* __restrict__ a_dst2,
    const float* __restrict__ b2, float* __restrict__ out)
{
    const int i = blockIdx.x * 256 + threadIdx.x;
    if (i >= N_NODES) return;

    const float as = a_src2[0], ad = a_dst2[0];
    const float xi = xp2[i];
    const float s0 = (as + ad) * xi;
    const float l0 = s0 > 0.f ? s0 : SLOPE * s0;
    const float wself = __expf(l0);

    float denom = wself, num = wself * xi;
    const int end = rowptr[i + 1];
    for (int j = rowptr[i]; j < end; ++j) {
        const float xsv = xp2[esrc[j]];
        const float lg = as * xsv + ad * xi;
        const float ll = lg > 0.f ? lg : SLOPE * lg;
        const float w = __expf(ll);
        denom += w;
        num += w * xsv;
    }
    out[i] = num / denom + b2[0];
}

extern "C" void kernel_launch(void* const* d_in, const int* in_sizes, int n_in,
                              void* d_out, int out_size, void* d_ws, size_t ws_size,
                              hipStream_t stream)
{
    const int* h   = (const int*)d_in[0];
    const int* ei  = (const int*)d_in[1];
    const int* nt  = (const int*)d_in[2];
    const float* emb    = (const float*)d_in[3];
    const float* W1     = (const float*)d_in[4];
    const float* a_src1 = (const float*)d_in[5];
    const float* a_dst1 = (const float*)d_in[6];
    const float* b1     = (const float*)d_in[7];
    const float* W2     = (const float*)d_in[8];
    const float* a_src2 = (const float*)d_in[9];
    const float* a_dst2 = (const float*)d_in[10];
    const float* b2     = (const float*)d_in[11];
    float* out = (float*)d_out;

    char* ws = (char*)d_ws;
    size_t off = 0;
    float* xp1    = (float*)(ws + off); off += (size_t)N_NODES * HD * sizeof(float);
    float* es1    = (float*)(ws + off); off += (size_t)N_NODES * sizeof(float);
    float* ed1    = (float*)(ws + off); off += (size_t)N_NODES * sizeof(float);
    float* denom1 = (float*)(ws + off); off += (size_t)N_NODES * sizeof(float);
    float* xp2    = (float*)(ws + off); off += (size_t)N_NODES * sizeof(float);
    int*   deg    = (int*)(ws + off);   off += (size_t)N_NODES * sizeof(int);
    int*   fill   = (int*)(ws + off);   off += (size_t)N_NODES * sizeof(int);
    int*   rowptr = (int*)(ws + off);   off += ((size_t)N_NODES + 1) * sizeof(int);
    int*   bsum   = (int*)(ws + off);   off += (size_t)NBLK * sizeof(int);
    int*   bscan  = (int*)(ws + off);   off += (size_t)NBLK * sizeof(int);
    int*   esrc   = (int*)(ws + off);   off += (size_t)N_EDGES * sizeof(int);
    float* ew     = (float*)(ws + off); off += (size_t)N_EDGES * sizeof(float);

    gemm1_kernel<<<N_NODES / TM, 256, 0, stream>>>(
        h, emb, W1, a_src1, a_dst1, xp1, es1, ed1, denom1);
    zero_kernel<<<NBLK, 256, 0, stream>>>(deg, fill);
    hist_kernel<<<(N_EDGES + 255) / 256, 256, 0, stream>>>(ei, nt, deg);
    bsum_kernel<<<NBLK, 256, 0, stream>>>(deg, bsum);
    bscan_kernel<<<1, 512, 0, stream>>>(bsum, bscan, rowptr);
    rowptr_kernel<<<NBLK, 256, 0, stream>>>(deg, bscan, rowptr);
    scatter_kernel<<<(N_EDGES + 255) / 256, 256, 0, stream>>>(
        ei, nt, es1, ed1, rowptr, fill, esrc, ew);
    gather1_kernel<<<(N_NODES + 3) / 4, 256, 0, stream>>>(
        xp1, denom1, rowptr, esrc, ew, b1, W2, xp2);
    final2_kernel<<<NBLK, 256, 0, stream>>>(
        xp2, rowptr, esrc, a_src2, a_dst2, b2, out);
}